// Round 3
// baseline (286.595 us; speedup 1.0000x reference)
//
#include <hip/hip_runtime.h>
#include <hip/hip_bf16.h>

typedef __attribute__((ext_vector_type(4))) float f32x4;
typedef __attribute__((ext_vector_type(8))) short bf16x8;

constexpr int Bn  = 4;
constexpr int Ln  = 1024;
constexpr int Dn  = 1024;
constexpr int Hn  = 16;
constexpr int HDn = 64;

static __device__ __forceinline__ unsigned short bf16r(float f) {
    union { float f; unsigned int u; } x;
    x.f = f;
    unsigned int r = x.u + 0x7fffu + ((x.u >> 16) & 1u);
    return (unsigned short)(r >> 16);
}

static __device__ __forceinline__ unsigned int pk2(float a, float b) {
    return (unsigned int)bf16r(a) | ((unsigned int)bf16r(b) << 16);
}

// ---------------------------------------------------------------------------
// Fused prep. grid (16,16,5) x 256 threads.  (unchanged)
// ---------------------------------------------------------------------------
__global__ __launch_bounds__(256) void prep_kernel(
    const float* __restrict__ Kg, const float* __restrict__ Vg,
    const float* __restrict__ Wg, unsigned short* __restrict__ Kbf,
    unsigned short* __restrict__ Vtg, unsigned short* __restrict__ Wbf)
{
    const int tid = threadIdx.x;
    if (blockIdx.z == 4) {
        const int r0 = blockIdx.x * 64, c0 = blockIdx.y * 64;
        for (int i = 0; i < 4; ++i) {
            int e4 = i * 256 + tid;
            int r = e4 >> 4, c4 = e4 & 15;
            const float* p = Wg + (size_t)(r0 + r) * Dn + c0 + c4 * 4;
            float4 v = *(const float4*)p;
            ushort4 o;
            o.x = bf16r(v.x); o.y = bf16r(v.y); o.z = bf16r(v.z); o.w = bf16r(v.w);
            *(ushort4*)(Wbf + (size_t)(r0 + r) * Dn + c0 + c4 * 4) = o;
        }
        return;
    }

    __shared__ unsigned short T[64][72];   // [d][k]
    const int k0 = blockIdx.x * 64;
    const int h  = blockIdx.y;
    const int b  = blockIdx.z;
    const float* Kb = Kg + (size_t)b * Ln * Dn + h * HDn;
    const float* Vb = Vg + (size_t)b * Ln * Dn + h * HDn;
    unsigned short* Ko = Kbf + (size_t)b * Ln * Dn + h * HDn;

    for (int i = 0; i < 4; ++i) {
        int e4 = i * 256 + tid;
        int r = e4 >> 4, c4 = e4 & 15;
        float4 kv = *(const float4*)(Kb + (size_t)(k0 + r) * Dn + c4 * 4);
        ushort4 o;
        o.x = bf16r(kv.x); o.y = bf16r(kv.y); o.z = bf16r(kv.z); o.w = bf16r(kv.w);
        *(ushort4*)(Ko + (size_t)(k0 + r) * Dn + c4 * 4) = o;
        float4 vv = *(const float4*)(Vb + (size_t)(k0 + r) * Dn + c4 * 4);
        T[c4 * 4 + 0][r] = bf16r(vv.x);
        T[c4 * 4 + 1][r] = bf16r(vv.y);
        T[c4 * 4 + 2][r] = bf16r(vv.z);
        T[c4 * 4 + 3][r] = bf16r(vv.w);
    }
    __syncthreads();
    unsigned short* out = Vtg + ((size_t)(b * Hn + h) * HDn) * Ln + k0;
    for (int i = 0; i < 2; ++i) {
        int e8 = i * 256 + tid;
        int r = e8 >> 3, c8 = e8 & 7;
        *(uint4*)(out + (size_t)r * Ln + c8 * 8) = *(const uint4*)&T[r][c8 * 8];
    }
}

// ---------------------------------------------------------------------------
// Flash attention, v3:
//  - exp2/rcp via __builtin_amdgcn_* (toolchain-proof: no libm call path,
//    which is what blew VALUBusy to 70% / SGPR to 112 on the last container).
//  - 2 blocks/CU: 256 threads (4 waves x 32 q-rows -> q-tile 128), grid 512.
//    Same per-wave fragment reuse as v2, but two independent barrier domains
//    per CU so one block's staging overlaps the other's MFMA.
//  - s_setprio(1) around the two MFMA clusters (T5).
//  - XCD decode: all 8 q-tiles of one (b,h) on one XCD (K/V set 2MB < L2).
// ---------------------------------------------------------------------------
__global__ __launch_bounds__(256) void attn_kernel(
    const float* __restrict__ Qg, const unsigned short* __restrict__ Kbf,
    const unsigned short* __restrict__ Vtg, unsigned short* __restrict__ Xg)
{
    __shared__ unsigned short Ks[64][72];
    __shared__ unsigned short Vts[64][72];    // [d][k]
    __shared__ unsigned short Ps[128][72];    // [q_local][k]

    const int tid  = threadIdx.x;
    const int wave = tid >> 6;     // 0..3
    const int lane = tid & 63;
    const int l16  = lane & 15;
    const int quad = lane >> 4;
    const int wb   = wave * 32;    // wave's q-row base within the 128-row tile

    // XCD-aware decode: flat = xcd + 8*(qt + 8*gg); (b,h) = xcd + 8*gg.
    const int flat = blockIdx.x;
    const int xcd  = flat & 7;
    const int j    = flat >> 3;    // 0..63
    const int qt   = j & 7;
    const int gg   = j >> 3;
    const int g    = xcd + 8 * gg; // 0..63
    const int h    = g & 15;
    const int b    = g >> 4;
    const int q0   = qt * 128;

    const unsigned short* Kb16 = Kbf + (size_t)b * Ln * Dn + h * HDn;
    const unsigned short* Vtb  = Vtg + ((size_t)(b * Hn + h) * HDn) * Ln;

    // Q fragments (read exactly once). B-operand layout: n=l16, k=quad*8+j.
    bf16x8 bq[2][2];
    for (int hf = 0; hf < 2; ++hf) {
        const float* qp = Qg + ((size_t)b * Ln + q0 + wb + hf * 16 + l16) * Dn
                             + h * HDn + quad * 8;
        float4 a0 = *(const float4*)qp;
        float4 a1 = *(const float4*)(qp + 4);
        float4 a2 = *(const float4*)(qp + 32);
        float4 a3 = *(const float4*)(qp + 36);
        bq[hf][0][0] = (short)bf16r(a0.x); bq[hf][0][1] = (short)bf16r(a0.y);
        bq[hf][0][2] = (short)bf16r(a0.z); bq[hf][0][3] = (short)bf16r(a0.w);
        bq[hf][0][4] = (short)bf16r(a1.x); bq[hf][0][5] = (short)bf16r(a1.y);
        bq[hf][0][6] = (short)bf16r(a1.z); bq[hf][0][7] = (short)bf16r(a1.w);
        bq[hf][1][0] = (short)bf16r(a2.x); bq[hf][1][1] = (short)bf16r(a2.y);
        bq[hf][1][2] = (short)bf16r(a2.z); bq[hf][1][3] = (short)bf16r(a2.w);
        bq[hf][1][4] = (short)bf16r(a3.x); bq[hf][1][5] = (short)bf16r(a3.y);
        bq[hf][1][6] = (short)bf16r(a3.z); bq[hf][1][7] = (short)bf16r(a3.w);
    }

    const float SC = 1.4426950408889634f / 32.0f;   // log2(e)/sqrt(D)

    float lsum[2] = {0.f, 0.f};
    f32x4 Oacc[2][4];
    for (int hf = 0; hf < 2; ++hf)
        for (int d = 0; d < 4; ++d) Oacc[hf][d] = (f32x4){0.f, 0.f, 0.f, 0.f};

    // Stage: 256 threads, two uint4 per array per tile.
    uint4 kreg[2], vreg[2];
    for (int i = 0; i < 2; ++i) {
        int idx = i * 256 + tid, r = idx >> 3, c = idx & 7;
        kreg[i] = *(const uint4*)(Kb16 + (size_t)r * Dn + c * 8);
        vreg[i] = *(const uint4*)(Vtb + (size_t)r * Ln + c * 8);
    }

    for (int it = 0; it < Ln / 64; ++it) {
        __syncthreads();   // previous tile's compute done -> Ks/Vts free
        for (int i = 0; i < 2; ++i) {
            int idx = i * 256 + tid, r = idx >> 3, c = idx & 7;
            *(uint4*)&Ks[r][c * 8]  = kreg[i];
            *(uint4*)&Vts[r][c * 8] = vreg[i];
        }
        if (it + 1 < Ln / 64) {   // prefetch next tile; latency hides under compute
            const int k1 = (it + 1) * 64;
            for (int i = 0; i < 2; ++i) {
                int idx = i * 256 + tid, r = idx >> 3, c = idx & 7;
                kreg[i] = *(const uint4*)(Kb16 + (size_t)(k1 + r) * Dn + c * 8);
                vreg[i] = *(const uint4*)(Vtb + (size_t)r * Ln + k1 + c * 8);
            }
        }
        __syncthreads();

        // S^T = K Q^T : A = K-frag (m=key), B = Q-frag (n=q). 8 reads, 16 MFMA.
        f32x4 st[2][4];
        __builtin_amdgcn_s_setprio(1);
        for (int n = 0; n < 4; ++n) {
            bf16x8 a0 = *(const bf16x8*)&Ks[n * 16 + l16][quad * 8];
            bf16x8 a1 = *(const bf16x8*)&Ks[n * 16 + l16][32 + quad * 8];
            for (int hf = 0; hf < 2; ++hf) {
                f32x4 acc = (f32x4){0.f, 0.f, 0.f, 0.f};
                acc = __builtin_amdgcn_mfma_f32_16x16x32_bf16(a0, bq[hf][0], acc, 0, 0, 0);
                acc = __builtin_amdgcn_mfma_f32_16x16x32_bf16(a1, bq[hf][1], acc, 0, 0, 0);
                st[hf][n] = acc;
            }
        }
        __builtin_amdgcn_s_setprio(0);

        // P = exp2(S^T * SC). Lane holds keys 16n+quad*4+(0..3) for q=l16:
        // k-consecutive -> pack pairs, one b64 store per n. Scalar row-sum.
        for (int hf = 0; hf < 2; ++hf) {
            float ls = 0.f;
            for (int n = 0; n < 4; ++n) {
                float p0 = __builtin_amdgcn_exp2f(st[hf][n][0] * SC);
                float p1 = __builtin_amdgcn_exp2f(st[hf][n][1] * SC);
                float p2 = __builtin_amdgcn_exp2f(st[hf][n][2] * SC);
                float p3 = __builtin_amdgcn_exp2f(st[hf][n][3] * SC);
                ls += (p0 + p1) + (p2 + p3);
                uint2 w;
                w.x = pk2(p0, p1);
                w.y = pk2(p2, p3);
                *(uint2*)&Ps[wb + hf * 16 + l16][n * 16 + quad * 4] = w;
            }
            lsum[hf] += ls;
        }

        // O += P V. V B-frags shared across the two q-halves.
        __builtin_amdgcn_s_setprio(1);
        for (int kk = 0; kk < 2; ++kk) {
            bf16x8 bv[4];
            for (int dt = 0; dt < 4; ++dt)
                bv[dt] = *(const bf16x8*)&Vts[dt * 16 + l16][kk * 32 + quad * 8];
            for (int hf = 0; hf < 2; ++hf) {
                bf16x8 ap = *(const bf16x8*)&Ps[wb + hf * 16 + l16][kk * 32 + quad * 8];
                for (int dt = 0; dt < 4; ++dt)
                    Oacc[hf][dt] = __builtin_amdgcn_mfma_f32_16x16x32_bf16(
                        ap, bv[dt], Oacc[hf][dt], 0, 0, 0);
            }
        }
        __builtin_amdgcn_s_setprio(0);
    }

    // Row sums live per-lane (q=l16); reduce across quads.
    float inv[2];
    for (int hf = 0; hf < 2; ++hf) {
        float rs = lsum[hf];
        rs += __shfl_xor(rs, 16, 64);
        rs += __shfl_xor(rs, 32, 64);
        inv[hf] = __builtin_amdgcn_rcpf(rs);
    }

    unsigned short* Xb = Xg + ((size_t)b * Ln + q0 + wb) * Dn + h * HDn;
    for (int hf = 0; hf < 2; ++hf)
        for (int r = 0; r < 4; ++r) {
            float iv = __shfl(inv[hf], quad * 4 + r, 64);
            int row = hf * 16 + quad * 4 + r;
            for (int dt = 0; dt < 4; ++dt)
                Xb[(size_t)row * Dn + dt * 16 + l16] = bf16r(Oacc[hf][dt][r] * iv);
        }
}

// ---------------------------------------------------------------------------
// Projection: Y = X @ W^T + b.  (unchanged)
// ---------------------------------------------------------------------------
__global__ __launch_bounds__(256) void proj_kernel(
    const unsigned short* __restrict__ Xg, const unsigned short* __restrict__ Wbf,
    const float* __restrict__ bg, float* __restrict__ Yg)
{
    __shared__ unsigned short Xs[64][136];
    __shared__ unsigned short Wsh[64][136];

    const int tid  = threadIdx.x;
    const int wave = tid >> 6;
    const int lane = tid & 63;
    const int l16  = lane & 15;
    const int quad = lane >> 4;
    const int mw   = (wave & 1) * 32;
    const int nw   = (wave >> 1) * 32;

    const int m0 = blockIdx.x * 64;
    const int n0 = blockIdx.y * 64;

    f32x4 acc[2][2];
    for (int mt = 0; mt < 2; ++mt)
        for (int nt = 0; nt < 2; ++nt)
            acc[mt][nt] = (f32x4){0.f, 0.f, 0.f, 0.f};

    for (int it = 0; it < Dn / 128; ++it) {
        const int kk0 = it * 128;
        __syncthreads();
        for (int i = 0; i < 4; ++i) {
            int idx = i * 256 + tid;
            int r = idx >> 4, c8 = idx & 15;
            *(uint4*)&Xs[r][c8 * 8] =
                *(const uint4*)(Xg + (size_t)(m0 + r) * Dn + kk0 + c8 * 8);
            *(uint4*)&Wsh[r][c8 * 8] =
                *(const uint4*)(Wbf + (size_t)(n0 + r) * Dn + kk0 + c8 * 8);
        }
        __syncthreads();

        for (int kk = 0; kk < 4; ++kk) {
            bf16x8 af[2], bfr[2];
            for (int mt = 0; mt < 2; ++mt)
                af[mt] = *(const bf16x8*)&Xs[mw + mt * 16 + l16][kk * 32 + quad * 8];
            for (int nt = 0; nt < 2; ++nt)
                bfr[nt] = *(const bf16x8*)&Wsh[nw + nt * 16 + l16][kk * 32 + quad * 8];
            for (int mt = 0; mt < 2; ++mt)
                for (int nt = 0; nt < 2; ++nt)
                    acc[mt][nt] = __builtin_amdgcn_mfma_f32_16x16x32_bf16(
                        af[mt], bfr[nt], acc[mt][nt], 0, 0, 0);
        }
    }

    for (int nt = 0; nt < 2; ++nt) {
        int col = n0 + nw + nt * 16 + l16;
        float bb = bg[col];
        for (int mt = 0; mt < 2; ++mt)
            for (int r = 0; r < 4; ++r) {
                int row = m0 + mw + mt * 16 + quad * 4 + r;
                Yg[(size_t)row * Dn + col] = acc[mt][nt][r] + bb;
            }
    }
}

extern "C" void kernel_launch(void* const* d_in, const int* in_sizes, int n_in,
                              void* d_out, int out_size, void* d_ws, size_t ws_size,
                              hipStream_t stream) {
    const float* Q    = (const float*)d_in[0];
    const float* K    = (const float*)d_in[1];
    const float* V    = (const float*)d_in[2];
    const float* W    = (const float*)d_in[3];
    const float* bias = (const float*)d_in[4];

    unsigned short* Kbf = (unsigned short*)d_ws;                  // 8 MB
    unsigned short* Vt  = Kbf + (size_t)Bn * Ln * Dn;             // 8 MB
    unsigned short* Wbf = Vt  + (size_t)Bn * Ln * Dn;             // 2 MB
    unsigned short* X   = Wbf + (size_t)Dn * Dn;                  // 8 MB
    float* Y = (float*)d_out;

    dim3 gp(Ln / 64, Hn, Bn + 1);        // z=0..3: K/V prep; z=4: W prep
    prep_kernel<<<gp, 256, 0, stream>>>(K, V, W, Kbf, Vt, Wbf);

    attn_kernel<<<dim3(512, 1, 1), 256, 0, stream>>>(Q, Kbf, Vt, X);

    dim3 g2((Bn * Ln) / 64, Dn / 64);    // 64 x 16 = 1024 blocks
    proj_kernel<<<g2, 256, 0, stream>>>(X, Wbf, bias, Y);
}

// Round 4
// 209.068 us; speedup vs baseline: 1.3708x; 1.3708x over previous
//
#include <hip/hip_runtime.h>
#include <hip/hip_bf16.h>

typedef __attribute__((ext_vector_type(4))) float f32x4;
typedef __attribute__((ext_vector_type(8))) short bf16x8;

constexpr int Bn  = 4;
constexpr int Ln  = 1024;
constexpr int Dn  = 1024;
constexpr int Hn  = 16;
constexpr int HDn = 64;

static __device__ __forceinline__ unsigned short bf16r(float f) {
    union { float f; unsigned int u; } x;
    x.f = f;
    unsigned int r = x.u + 0x7fffu + ((x.u >> 16) & 1u);
    return (unsigned short)(r >> 16);
}

static __device__ __forceinline__ unsigned int pk2(float a, float b) {
    return (unsigned int)bf16r(a) | ((unsigned int)bf16r(b) << 16);
}

// ---------------------------------------------------------------------------
// Fused prep. grid (16,16,5) x 256 threads.  (unchanged)
// ---------------------------------------------------------------------------
__global__ __launch_bounds__(256) void prep_kernel(
    const float* __restrict__ Kg, const float* __restrict__ Vg,
    const float* __restrict__ Wg, unsigned short* __restrict__ Kbf,
    unsigned short* __restrict__ Vtg, unsigned short* __restrict__ Wbf)
{
    const int tid = threadIdx.x;
    if (blockIdx.z == 4) {
        const int r0 = blockIdx.x * 64, c0 = blockIdx.y * 64;
        for (int i = 0; i < 4; ++i) {
            int e4 = i * 256 + tid;
            int r = e4 >> 4, c4 = e4 & 15;
            const float* p = Wg + (size_t)(r0 + r) * Dn + c0 + c4 * 4;
            float4 v = *(const float4*)p;
            ushort4 o;
            o.x = bf16r(v.x); o.y = bf16r(v.y); o.z = bf16r(v.z); o.w = bf16r(v.w);
            *(ushort4*)(Wbf + (size_t)(r0 + r) * Dn + c0 + c4 * 4) = o;
        }
        return;
    }

    __shared__ unsigned short T[64][72];   // [d][k]
    const int k0 = blockIdx.x * 64;
    const int h  = blockIdx.y;
    const int b  = blockIdx.z;
    const float* Kb = Kg + (size_t)b * Ln * Dn + h * HDn;
    const float* Vb = Vg + (size_t)b * Ln * Dn + h * HDn;
    unsigned short* Ko = Kbf + (size_t)b * Ln * Dn + h * HDn;

    for (int i = 0; i < 4; ++i) {
        int e4 = i * 256 + tid;
        int r = e4 >> 4, c4 = e4 & 15;
        float4 kv = *(const float4*)(Kb + (size_t)(k0 + r) * Dn + c4 * 4);
        ushort4 o;
        o.x = bf16r(kv.x); o.y = bf16r(kv.y); o.z = bf16r(kv.z); o.w = bf16r(kv.w);
        *(ushort4*)(Ko + (size_t)(k0 + r) * Dn + c4 * 4) = o;
        float4 vv = *(const float4*)(Vb + (size_t)(k0 + r) * Dn + c4 * 4);
        T[c4 * 4 + 0][r] = bf16r(vv.x);
        T[c4 * 4 + 1][r] = bf16r(vv.y);
        T[c4 * 4 + 2][r] = bf16r(vv.z);
        T[c4 * 4 + 3][r] = bf16r(vv.w);
    }
    __syncthreads();
    unsigned short* out = Vtg + ((size_t)(b * Hn + h) * HDn) * Ln + k0;
    for (int i = 0; i < 2; ++i) {
        int e8 = i * 256 + tid;
        int r = e8 >> 3, c8 = e8 & 7;
        *(uint4*)(out + (size_t)r * Ln + c8 * 8) = *(const uint4*)&T[r][c8 * 8];
    }
}

// ---------------------------------------------------------------------------
// Flash attention, v4 = v2 structure (512 thr, 8 waves x 32 q-rows, q-tile
// 256, grid 256, XCD decode), made toolchain-proof:
//  - LDS declared as NATIVE VECTOR types (uint4/uint2) so ds_write_b128/b64
//    cannot be scalarized by older compilers (rounds 2/3 showed 4.7x bank
//    conflicts + 10x VALU on byte-identical source -> punned-store scalarize).
//  - global K/V staging through typed const uint4* (no ushort punning).
//  - exp2/rcp via __builtin_amdgcn_* (no libm call path).
//  - T5 setprio around MFMA clusters.
// ---------------------------------------------------------------------------
__global__ __launch_bounds__(512) void attn_kernel(
    const float* __restrict__ Qg, const unsigned short* __restrict__ Kbf,
    const unsigned short* __restrict__ Vtg, unsigned short* __restrict__ Xg)
{
    __shared__ uint4 Ks4[64][9];     // 64 rows x 72 shorts (8 pad shorts)
    __shared__ uint4 Vts4[64][9];    // [d][k], same padding
    __shared__ uint2 Ps2[256][18];   // 256 rows x 72 shorts

    const int tid  = threadIdx.x;
    const int wave = tid >> 6;     // 0..7
    const int lane = tid & 63;
    const int l16  = lane & 15;
    const int quad = lane >> 4;
    const int wb   = wave * 32;    // wave's q-row base within the 256-row tile

    // XCD-aware decode: flat = xcd + 8*(qt + 4*gg); bh = xcd + 8*gg.
    const int flat = blockIdx.x;
    const int xcd  = flat & 7;
    const int j    = flat >> 3;
    const int qt   = j & 3;
    const int gg   = j >> 2;
    const int g    = xcd + 8 * gg;   // 0..63
    const int h    = g & 15;
    const int b    = g >> 4;
    const int q0   = qt * 256;

    const uint4* Kb4  = (const uint4*)(Kbf + (size_t)b * Ln * Dn + h * HDn);
    const uint4* Vtb4 = (const uint4*)(Vtg + ((size_t)(b * Hn + h) * HDn) * Ln);
    // row strides in uint4 units: K rows are Dn shorts = 128 uint4;
    // Vt rows are Ln shorts = 128 uint4.

    // Q fragments (read exactly once). B-operand layout: n=l16, k=quad*8+j.
    bf16x8 bq[2][2];
    for (int hf = 0; hf < 2; ++hf) {
        const float* qp = Qg + ((size_t)b * Ln + q0 + wb + hf * 16 + l16) * Dn
                             + h * HDn + quad * 8;
        float4 a0 = *(const float4*)qp;
        float4 a1 = *(const float4*)(qp + 4);
        float4 a2 = *(const float4*)(qp + 32);
        float4 a3 = *(const float4*)(qp + 36);
        bq[hf][0][0] = (short)bf16r(a0.x); bq[hf][0][1] = (short)bf16r(a0.y);
        bq[hf][0][2] = (short)bf16r(a0.z); bq[hf][0][3] = (short)bf16r(a0.w);
        bq[hf][0][4] = (short)bf16r(a1.x); bq[hf][0][5] = (short)bf16r(a1.y);
        bq[hf][0][6] = (short)bf16r(a1.z); bq[hf][0][7] = (short)bf16r(a1.w);
        bq[hf][1][0] = (short)bf16r(a2.x); bq[hf][1][1] = (short)bf16r(a2.y);
        bq[hf][1][2] = (short)bf16r(a2.z); bq[hf][1][3] = (short)bf16r(a2.w);
        bq[hf][1][4] = (short)bf16r(a3.x); bq[hf][1][5] = (short)bf16r(a3.y);
        bq[hf][1][6] = (short)bf16r(a3.z); bq[hf][1][7] = (short)bf16r(a3.w);
    }

    const float SC = 1.4426950408889634f / 32.0f;   // log2(e)/sqrt(D)

    float lsum[2] = {0.f, 0.f};
    f32x4 Oacc[2][4];
    for (int hf = 0; hf < 2; ++hf)
        for (int d = 0; d < 4; ++d) Oacc[hf][d] = (f32x4){0.f, 0.f, 0.f, 0.f};

    // Stage addressing: 512 threads, one uint4 per array per tile.
    const int sr = tid >> 3, sc = tid & 7;
    uint4 kreg, vreg;
    {   // preload tile 0
        kreg = Kb4[(size_t)sr * 128 + sc];
        vreg = Vtb4[(size_t)sr * 128 + sc];
    }

    for (int it = 0; it < Ln / 64; ++it) {
        __syncthreads();   // previous tile's compute done -> Ks/Vts free
        Ks4[sr][sc]  = kreg;
        Vts4[sr][sc] = vreg;
        if (it + 1 < Ln / 64) {   // prefetch next tile; hides under compute
            const int c1 = (it + 1) * 8;   // k-offset in uint4 units
            kreg = Kb4[(size_t)(((it + 1) * 64) + sr) * 128 + sc];
            vreg = Vtb4[(size_t)sr * 128 + c1 + sc];
        }
        __syncthreads();

        // S^T = K Q^T : A = K-frag (m=key), B = Q-frag (n=q). 8 reads, 16 MFMA.
        f32x4 st[2][4];
        __builtin_amdgcn_s_setprio(1);
        for (int n = 0; n < 4; ++n) {
            bf16x8 a0 = *(const bf16x8*)&Ks4[n * 16 + l16][quad];
            bf16x8 a1 = *(const bf16x8*)&Ks4[n * 16 + l16][4 + quad];
            for (int hf = 0; hf < 2; ++hf) {
                f32x4 acc = (f32x4){0.f, 0.f, 0.f, 0.f};
                acc = __builtin_amdgcn_mfma_f32_16x16x32_bf16(a0, bq[hf][0], acc, 0, 0, 0);
                acc = __builtin_amdgcn_mfma_f32_16x16x32_bf16(a1, bq[hf][1], acc, 0, 0, 0);
                st[hf][n] = acc;
            }
        }
        __builtin_amdgcn_s_setprio(0);

        // P = exp2(S^T * SC). Lane holds keys 16n+quad*4+(0..3) for q=l16:
        // k-consecutive -> pack pairs, one b64 store per n. Scalar row-sum.
        for (int hf = 0; hf < 2; ++hf) {
            float ls = 0.f;
            for (int n = 0; n < 4; ++n) {
                float p0 = __builtin_amdgcn_exp2f(st[hf][n][0] * SC);
                float p1 = __builtin_amdgcn_exp2f(st[hf][n][1] * SC);
                float p2 = __builtin_amdgcn_exp2f(st[hf][n][2] * SC);
                float p3 = __builtin_amdgcn_exp2f(st[hf][n][3] * SC);
                ls += (p0 + p1) + (p2 + p3);
                uint2 w;
                w.x = pk2(p0, p1);
                w.y = pk2(p2, p3);
                Ps2[wb + hf * 16 + l16][n * 4 + quad] = w;
            }
            lsum[hf] += ls;
        }

        // O += P V. V B-frags shared across the two q-halves.
        __builtin_amdgcn_s_setprio(1);
        for (int kk = 0; kk < 2; ++kk) {
            bf16x8 bv[4];
            for (int dt = 0; dt < 4; ++dt)
                bv[dt] = *(const bf16x8*)&Vts4[dt * 16 + l16][kk * 4 + quad];
            for (int hf = 0; hf < 2; ++hf) {
                bf16x8 ap = *(const bf16x8*)&Ps2[wb + hf * 16 + l16][kk * 8 + quad * 2];
                for (int dt = 0; dt < 4; ++dt)
                    Oacc[hf][dt] = __builtin_amdgcn_mfma_f32_16x16x32_bf16(
                        ap, bv[dt], Oacc[hf][dt], 0, 0, 0);
            }
        }
        __builtin_amdgcn_s_setprio(0);
    }

    // Row sums live per-lane (q=l16); reduce across quads.
    float inv[2];
    for (int hf = 0; hf < 2; ++hf) {
        float rs = lsum[hf];
        rs += __shfl_xor(rs, 16, 64);
        rs += __shfl_xor(rs, 32, 64);
        inv[hf] = __builtin_amdgcn_rcpf(rs);
    }

    unsigned short* Xb = Xg + ((size_t)b * Ln + q0 + wb) * Dn + h * HDn;
    for (int hf = 0; hf < 2; ++hf)
        for (int r = 0; r < 4; ++r) {
            float iv = __shfl(inv[hf], quad * 4 + r, 64);
            int row = hf * 16 + quad * 4 + r;
            for (int dt = 0; dt < 4; ++dt)
                Xb[(size_t)row * Dn + dt * 16 + l16] = bf16r(Oacc[hf][dt][r] * iv);
        }
}

// ---------------------------------------------------------------------------
// Projection: Y = X @ W^T + b.  (unchanged structure; proven stable)
// ---------------------------------------------------------------------------
__global__ __launch_bounds__(256) void proj_kernel(
    const unsigned short* __restrict__ Xg, const unsigned short* __restrict__ Wbf,
    const float* __restrict__ bg, float* __restrict__ Yg)
{
    __shared__ unsigned short Xs[64][136];
    __shared__ unsigned short Wsh[64][136];

    const int tid  = threadIdx.x;
    const int wave = tid >> 6;
    const int lane = tid & 63;
    const int l16  = lane & 15;
    const int quad = lane >> 4;
    const int mw   = (wave & 1) * 32;
    const int nw   = (wave >> 1) * 32;

    const int m0 = blockIdx.x * 64;
    const int n0 = blockIdx.y * 64;

    f32x4 acc[2][2];
    for (int mt = 0; mt < 2; ++mt)
        for (int nt = 0; nt < 2; ++nt)
            acc[mt][nt] = (f32x4){0.f, 0.f, 0.f, 0.f};

    for (int it = 0; it < Dn / 128; ++it) {
        const int kk0 = it * 128;
        __syncthreads();
        for (int i = 0; i < 4; ++i) {
            int idx = i * 256 + tid;
            int r = idx >> 4, c8 = idx & 15;
            *(uint4*)&Xs[r][c8 * 8] =
                *(const uint4*)(Xg + (size_t)(m0 + r) * Dn + kk0 + c8 * 8);
            *(uint4*)&Wsh[r][c8 * 8] =
                *(const uint4*)(Wbf + (size_t)(n0 + r) * Dn + kk0 + c8 * 8);
        }
        __syncthreads();

        for (int kk = 0; kk < 4; ++kk) {
            bf16x8 af[2], bfr[2];
            for (int mt = 0; mt < 2; ++mt)
                af[mt] = *(const bf16x8*)&Xs[mw + mt * 16 + l16][kk * 32 + quad * 8];
            for (int nt = 0; nt < 2; ++nt)
                bfr[nt] = *(const bf16x8*)&Wsh[nw + nt * 16 + l16][kk * 32 + quad * 8];
            for (int mt = 0; mt < 2; ++mt)
                for (int nt = 0; nt < 2; ++nt)
                    acc[mt][nt] = __builtin_amdgcn_mfma_f32_16x16x32_bf16(
                        af[mt], bfr[nt], acc[mt][nt], 0, 0, 0);
        }
    }

    for (int nt = 0; nt < 2; ++nt) {
        int col = n0 + nw + nt * 16 + l16;
        float bb = bg[col];
        for (int mt = 0; mt < 2; ++mt)
            for (int r = 0; r < 4; ++r) {
                int row = m0 + mw + mt * 16 + quad * 4 + r;
                Yg[(size_t)row * Dn + col] = acc[mt][nt][r] + bb;
            }
    }
}

extern "C" void kernel_launch(void* const* d_in, const int* in_sizes, int n_in,
                              void* d_out, int out_size, void* d_ws, size_t ws_size,
                              hipStream_t stream) {
    const float* Q    = (const float*)d_in[0];
    const float* K    = (const float*)d_in[1];
    const float* V    = (const float*)d_in[2];
    const float* W    = (const float*)d_in[3];
    const float* bias = (const float*)d_in[4];

    unsigned short* Kbf = (unsigned short*)d_ws;                  // 8 MB
    unsigned short* Vt  = Kbf + (size_t)Bn * Ln * Dn;             // 8 MB
    unsigned short* Wbf = Vt  + (size_t)Bn * Ln * Dn;             // 2 MB
    unsigned short* X   = Wbf + (size_t)Dn * Dn;                  // 8 MB
    float* Y = (float*)d_out;

    dim3 gp(Ln / 64, Hn, Bn + 1);        // z=0..3: K/V prep; z=4: W prep
    prep_kernel<<<gp, 256, 0, stream>>>(K, V, W, Kbf, Vt, Wbf);

    attn_kernel<<<dim3(256, 1, 1), 512, 0, stream>>>(Q, Kbf, Vt, X);

    dim3 g2((Bn * Ln) / 64, Dn / 64);    // 64 x 16 = 1024 blocks
    proj_kernel<<<g2, 256, 0, stream>>>(X, Wbf, bias, Y);
}

// Round 5
// 148.921 us; speedup vs baseline: 1.9245x; 1.4039x over previous
//
#include <hip/hip_runtime.h>
#include <hip/hip_bf16.h>

typedef __attribute__((ext_vector_type(4))) float f32x4;
typedef __attribute__((ext_vector_type(8))) short bf16x8;

constexpr int Bn  = 4;
constexpr int Ln  = 1024;
constexpr int Dn  = 1024;
constexpr int Hn  = 16;
constexpr int HDn = 64;

static __device__ __forceinline__ unsigned short bf16r(float f) {
    union { float f; unsigned int u; } x;
    x.f = f;
    unsigned int r = x.u + 0x7fffu + ((x.u >> 16) & 1u);
    return (unsigned short)(r >> 16);
}

static __device__ __forceinline__ unsigned int pk2(float a, float b) {
    return (unsigned int)bf16r(a) | ((unsigned int)bf16r(b) << 16);
}

// ---------------------------------------------------------------------------
// Fused prep. grid (16,16,5) x 256 threads.
// ---------------------------------------------------------------------------
__global__ __launch_bounds__(256) void prep_kernel(
    const float* __restrict__ Kg, const float* __restrict__ Vg,
    const float* __restrict__ Wg, unsigned short* __restrict__ Kbf,
    unsigned short* __restrict__ Vtg, unsigned short* __restrict__ Wbf)
{
    const int tid = threadIdx.x;
    if (blockIdx.z == 4) {
        const int r0 = blockIdx.x * 64, c0 = blockIdx.y * 64;
#pragma unroll 4
        for (int i = 0; i < 4; ++i) {
            int e4 = i * 256 + tid;
            int r = e4 >> 4, c4 = e4 & 15;
            const float* p = Wg + (size_t)(r0 + r) * Dn + c0 + c4 * 4;
            float4 v = *(const float4*)p;
            ushort4 o;
            o.x = bf16r(v.x); o.y = bf16r(v.y); o.z = bf16r(v.z); o.w = bf16r(v.w);
            *(ushort4*)(Wbf + (size_t)(r0 + r) * Dn + c0 + c4 * 4) = o;
        }
        return;
    }

    __shared__ unsigned short T[64][72];   // [d][k]
    const int k0 = blockIdx.x * 64;
    const int h  = blockIdx.y;
    const int b  = blockIdx.z;
    const float* Kb = Kg + (size_t)b * Ln * Dn + h * HDn;
    const float* Vb = Vg + (size_t)b * Ln * Dn + h * HDn;
    unsigned short* Ko = Kbf + (size_t)b * Ln * Dn + h * HDn;

#pragma unroll 4
    for (int i = 0; i < 4; ++i) {
        int e4 = i * 256 + tid;
        int r = e4 >> 4, c4 = e4 & 15;
        float4 kv = *(const float4*)(Kb + (size_t)(k0 + r) * Dn + c4 * 4);
        ushort4 o;
        o.x = bf16r(kv.x); o.y = bf16r(kv.y); o.z = bf16r(kv.z); o.w = bf16r(kv.w);
        *(ushort4*)(Ko + (size_t)(k0 + r) * Dn + c4 * 4) = o;
        float4 vv = *(const float4*)(Vb + (size_t)(k0 + r) * Dn + c4 * 4);
        T[c4 * 4 + 0][r] = bf16r(vv.x);
        T[c4 * 4 + 1][r] = bf16r(vv.y);
        T[c4 * 4 + 2][r] = bf16r(vv.z);
        T[c4 * 4 + 3][r] = bf16r(vv.w);
    }
    __syncthreads();
    unsigned short* out = Vtg + ((size_t)(b * Hn + h) * HDn) * Ln + k0;
#pragma unroll 2
    for (int i = 0; i < 2; ++i) {
        int e8 = i * 256 + tid;
        int r = e8 >> 3, c8 = e8 & 7;
        *(uint4*)(out + (size_t)r * Ln + c8 * 8) = *(const uint4*)&T[r][c8 * 8];
    }
}

// ---------------------------------------------------------------------------
// Flash attention, v5 = v4 + EXPLICIT #pragma unroll on every constant-trip
// loop that indexes a register array (st/bq/Oacc/bv/ap). Theory: the slow-
// container compiler (fingerprint SGPR=112, VGPR=64, 9x VALU) does NOT
// auto-unroll these, leaving register arrays runtime-indexed -> scratch
// (rule #20). Forced unrolling makes every index compile-time-constant on
// any toolchain. Structure unchanged from the 33 us round-1 kernel.
// ---------------------------------------------------------------------------
__global__ __launch_bounds__(512) void attn_kernel(
    const float* __restrict__ Qg, const unsigned short* __restrict__ Kbf,
    const unsigned short* __restrict__ Vtg, unsigned short* __restrict__ Xg)
{
    __shared__ uint4 Ks4[64][9];     // 64 rows x 72 shorts (8 pad shorts)
    __shared__ uint4 Vts4[64][9];    // [d][k], same padding
    __shared__ uint2 Ps2[256][18];   // 256 rows x 72 shorts

    const int tid  = threadIdx.x;
    const int wave = tid >> 6;     // 0..7
    const int lane = tid & 63;
    const int l16  = lane & 15;
    const int quad = lane >> 4;
    const int wb   = wave * 32;    // wave's q-row base within the 256-row tile

    // XCD-aware decode: flat = xcd + 8*(qt + 4*gg); bh = xcd + 8*gg.
    const int flat = blockIdx.x;
    const int xcd  = flat & 7;
    const int j    = flat >> 3;
    const int qt   = j & 3;
    const int gg   = j >> 2;
    const int g    = xcd + 8 * gg;   // 0..63
    const int h    = g & 15;
    const int b    = g >> 4;
    const int q0   = qt * 256;

    const uint4* Kb4  = (const uint4*)(Kbf + (size_t)b * Ln * Dn + h * HDn);
    const uint4* Vtb4 = (const uint4*)(Vtg + ((size_t)(b * Hn + h) * HDn) * Ln);

    // Q fragments (read exactly once). B-operand layout: n=l16, k=quad*8+j.
    bf16x8 bq[2][2];
#pragma unroll 2
    for (int hf = 0; hf < 2; ++hf) {
        const float* qp = Qg + ((size_t)b * Ln + q0 + wb + hf * 16 + l16) * Dn
                             + h * HDn + quad * 8;
        float4 a0 = *(const float4*)qp;
        float4 a1 = *(const float4*)(qp + 4);
        float4 a2 = *(const float4*)(qp + 32);
        float4 a3 = *(const float4*)(qp + 36);
        bq[hf][0][0] = (short)bf16r(a0.x); bq[hf][0][1] = (short)bf16r(a0.y);
        bq[hf][0][2] = (short)bf16r(a0.z); bq[hf][0][3] = (short)bf16r(a0.w);
        bq[hf][0][4] = (short)bf16r(a1.x); bq[hf][0][5] = (short)bf16r(a1.y);
        bq[hf][0][6] = (short)bf16r(a1.z); bq[hf][0][7] = (short)bf16r(a1.w);
        bq[hf][1][0] = (short)bf16r(a2.x); bq[hf][1][1] = (short)bf16r(a2.y);
        bq[hf][1][2] = (short)bf16r(a2.z); bq[hf][1][3] = (short)bf16r(a2.w);
        bq[hf][1][4] = (short)bf16r(a3.x); bq[hf][1][5] = (short)bf16r(a3.y);
        bq[hf][1][6] = (short)bf16r(a3.z); bq[hf][1][7] = (short)bf16r(a3.w);
    }

    const float SC = 1.4426950408889634f / 32.0f;   // log2(e)/sqrt(D)

    float lsum[2] = {0.f, 0.f};
    f32x4 Oacc[2][4];
#pragma unroll 2
    for (int hf = 0; hf < 2; ++hf)
#pragma unroll 4
        for (int d = 0; d < 4; ++d) Oacc[hf][d] = (f32x4){0.f, 0.f, 0.f, 0.f};

    // Stage addressing: 512 threads, one uint4 per array per tile.
    const int sr = tid >> 3, sc = tid & 7;
    uint4 kreg, vreg;
    {   // preload tile 0
        kreg = Kb4[(size_t)sr * 128 + sc];
        vreg = Vtb4[(size_t)sr * 128 + sc];
    }

    for (int it = 0; it < Ln / 64; ++it) {
        __syncthreads();   // previous tile's compute done -> Ks/Vts free
        Ks4[sr][sc]  = kreg;
        Vts4[sr][sc] = vreg;
        if (it + 1 < Ln / 64) {   // prefetch next tile; hides under compute
            kreg = Kb4[(size_t)(((it + 1) * 64) + sr) * 128 + sc];
            vreg = Vtb4[(size_t)sr * 128 + (it + 1) * 8 + sc];
        }
        __syncthreads();

        // S^T = K Q^T : A = K-frag (m=key), B = Q-frag (n=q). 8 reads, 16 MFMA.
        f32x4 st[2][4];
        __builtin_amdgcn_s_setprio(1);
#pragma unroll 4
        for (int n = 0; n < 4; ++n) {
            bf16x8 a0 = *(const bf16x8*)&Ks4[n * 16 + l16][quad];
            bf16x8 a1 = *(const bf16x8*)&Ks4[n * 16 + l16][4 + quad];
#pragma unroll 2
            for (int hf = 0; hf < 2; ++hf) {
                f32x4 acc = (f32x4){0.f, 0.f, 0.f, 0.f};
                acc = __builtin_amdgcn_mfma_f32_16x16x32_bf16(a0, bq[hf][0], acc, 0, 0, 0);
                acc = __builtin_amdgcn_mfma_f32_16x16x32_bf16(a1, bq[hf][1], acc, 0, 0, 0);
                st[hf][n] = acc;
            }
        }
        __builtin_amdgcn_s_setprio(0);

        // P = exp2(S^T * SC). Lane holds keys 16n+quad*4+(0..3) for q=l16:
        // k-consecutive -> pack pairs, one b64 store per n. Scalar row-sum.
#pragma unroll 2
        for (int hf = 0; hf < 2; ++hf) {
            float ls = 0.f;
#pragma unroll 4
            for (int n = 0; n < 4; ++n) {
                float p0 = __builtin_amdgcn_exp2f(st[hf][n][0] * SC);
                float p1 = __builtin_amdgcn_exp2f(st[hf][n][1] * SC);
                float p2 = __builtin_amdgcn_exp2f(st[hf][n][2] * SC);
                float p3 = __builtin_amdgcn_exp2f(st[hf][n][3] * SC);
                ls += (p0 + p1) + (p2 + p3);
                uint2 w;
                w.x = pk2(p0, p1);
                w.y = pk2(p2, p3);
                Ps2[wb + hf * 16 + l16][n * 4 + quad] = w;
            }
            lsum[hf] += ls;
        }

        // O += P V. V B-frags shared across the two q-halves.
        __builtin_amdgcn_s_setprio(1);
#pragma unroll 2
        for (int kk = 0; kk < 2; ++kk) {
            bf16x8 bv[4];
#pragma unroll 4
            for (int dt = 0; dt < 4; ++dt)
                bv[dt] = *(const bf16x8*)&Vts4[dt * 16 + l16][kk * 4 + quad];
#pragma unroll 2
            for (int hf = 0; hf < 2; ++hf) {
                bf16x8 ap = *(const bf16x8*)&Ps2[wb + hf * 16 + l16][kk * 8 + quad * 2];
#pragma unroll 4
                for (int dt = 0; dt < 4; ++dt)
                    Oacc[hf][dt] = __builtin_amdgcn_mfma_f32_16x16x32_bf16(
                        ap, bv[dt], Oacc[hf][dt], 0, 0, 0);
            }
        }
        __builtin_amdgcn_s_setprio(0);
    }

    // Row sums live per-lane (q=l16); reduce across quads.
    float inv[2];
#pragma unroll 2
    for (int hf = 0; hf < 2; ++hf) {
        float rs = lsum[hf];
        rs += __shfl_xor(rs, 16, 64);
        rs += __shfl_xor(rs, 32, 64);
        inv[hf] = __builtin_amdgcn_rcpf(rs);
    }

    unsigned short* Xb = Xg + ((size_t)b * Ln + q0 + wb) * Dn + h * HDn;
#pragma unroll 2
    for (int hf = 0; hf < 2; ++hf)
#pragma unroll 4
        for (int r = 0; r < 4; ++r) {
            float iv = __shfl(inv[hf], quad * 4 + r, 64);
            int row = hf * 16 + quad * 4 + r;
#pragma unroll 4
            for (int dt = 0; dt < 4; ++dt)
                Xb[(size_t)row * Dn + dt * 16 + l16] = bf16r(Oacc[hf][dt][r] * iv);
        }
}

// ---------------------------------------------------------------------------
// Projection: Y = X @ W^T + b.  (structure unchanged; loops force-unrolled)
// ---------------------------------------------------------------------------
__global__ __launch_bounds__(256) void proj_kernel(
    const unsigned short* __restrict__ Xg, const unsigned short* __restrict__ Wbf,
    const float* __restrict__ bg, float* __restrict__ Yg)
{
    __shared__ unsigned short Xs[64][136];
    __shared__ unsigned short Wsh[64][136];

    const int tid  = threadIdx.x;
    const int wave = tid >> 6;
    const int lane = tid & 63;
    const int l16  = lane & 15;
    const int quad = lane >> 4;
    const int mw   = (wave & 1) * 32;
    const int nw   = (wave >> 1) * 32;

    const int m0 = blockIdx.x * 64;
    const int n0 = blockIdx.y * 64;

    f32x4 acc[2][2];
#pragma unroll 2
    for (int mt = 0; mt < 2; ++mt)
#pragma unroll 2
        for (int nt = 0; nt < 2; ++nt)
            acc[mt][nt] = (f32x4){0.f, 0.f, 0.f, 0.f};

    for (int it = 0; it < Dn / 128; ++it) {
        const int kk0 = it * 128;
        __syncthreads();
#pragma unroll 4
        for (int i = 0; i < 4; ++i) {
            int idx = i * 256 + tid;
            int r = idx >> 4, c8 = idx & 15;
            *(uint4*)&Xs[r][c8 * 8] =
                *(const uint4*)(Xg + (size_t)(m0 + r) * Dn + kk0 + c8 * 8);
            *(uint4*)&Wsh[r][c8 * 8] =
                *(const uint4*)(Wbf + (size_t)(n0 + r) * Dn + kk0 + c8 * 8);
        }
        __syncthreads();

#pragma unroll 4
        for (int kk = 0; kk < 4; ++kk) {
            bf16x8 af[2], bfr[2];
#pragma unroll 2
            for (int mt = 0; mt < 2; ++mt)
                af[mt] = *(const bf16x8*)&Xs[mw + mt * 16 + l16][kk * 32 + quad * 8];
#pragma unroll 2
            for (int nt = 0; nt < 2; ++nt)
                bfr[nt] = *(const bf16x8*)&Wsh[nw + nt * 16 + l16][kk * 32 + quad * 8];
#pragma unroll 2
            for (int mt = 0; mt < 2; ++mt)
#pragma unroll 2
                for (int nt = 0; nt < 2; ++nt)
                    acc[mt][nt] = __builtin_amdgcn_mfma_f32_16x16x32_bf16(
                        af[mt], bfr[nt], acc[mt][nt], 0, 0, 0);
        }
    }

#pragma unroll 2
    for (int nt = 0; nt < 2; ++nt) {
        int col = n0 + nw + nt * 16 + l16;
        float bb = bg[col];
#pragma unroll 2
        for (int mt = 0; mt < 2; ++mt)
#pragma unroll 4
            for (int r = 0; r < 4; ++r) {
                int row = m0 + mw + mt * 16 + quad * 4 + r;
                Yg[(size_t)row * Dn + col] = acc[mt][nt][r] + bb;
            }
    }
}

extern "C" void kernel_launch(void* const* d_in, const int* in_sizes, int n_in,
                              void* d_out, int out_size, void* d_ws, size_t ws_size,
                              hipStream_t stream) {
    const float* Q    = (const float*)d_in[0];
    const float* K    = (const float*)d_in[1];
    const float* V    = (const float*)d_in[2];
    const float* W    = (const float*)d_in[3];
    const float* bias = (const float*)d_in[4];

    unsigned short* Kbf = (unsigned short*)d_ws;                  // 8 MB
    unsigned short* Vt  = Kbf + (size_t)Bn * Ln * Dn;             // 8 MB
    unsigned short* Wbf = Vt  + (size_t)Bn * Ln * Dn;             // 2 MB
    unsigned short* X   = Wbf + (size_t)Dn * Dn;                  // 8 MB
    float* Y = (float*)d_out;

    dim3 gp(Ln / 64, Hn, Bn + 1);        // z=0..3: K/V prep; z=4: W prep
    prep_kernel<<<gp, 256, 0, stream>>>(K, V, W, Kbf, Vt, Wbf);

    attn_kernel<<<dim3(256, 1, 1), 512, 0, stream>>>(Q, Kbf, Vt, X);

    dim3 g2((Bn * Ln) / 64, Dn / 64);    // 64 x 16 = 1024 blocks
    proj_kernel<<<g2, 256, 0, stream>>>(X, Wbf, bias, Y);
}